// Round 1
// baseline (1447.480 us; speedup 1.0000x reference)
//
#include <hip/hip_runtime.h>

#define NN 100000
#define NE 1600000

typedef __bf16 bf16;
typedef bf16 bf16x8 __attribute__((ext_vector_type(8)));
typedef bf16 bf16x4 __attribute__((ext_vector_type(4)));
typedef float f32x4 __attribute__((ext_vector_type(4)));

__device__ __forceinline__ f32x4 mfma16(bf16x8 a, bf16x8 b, f32x4 c) {
    return __builtin_amdgcn_mfma_f32_16x16x32_bf16(a, b, c, 0, 0, 0);
}

// ---------------- fp32 -> bf16 conversion (weights, x) ----------------
__global__ void cvt_kernel(const float* __restrict__ s, bf16* __restrict__ d, int n4) {
    int i = blockIdx.x * 256 + threadIdx.x;
    if (i < n4) {
        f32x4 v = ((const f32x4*)s)[i];
        bf16x4 o;
        o[0] = (bf16)v[0]; o[1] = (bf16)v[1]; o[2] = (bf16)v[2]; o[3] = (bf16)v[3];
        ((bf16x4*)d)[i] = o;
    }
}

// ---------------- node kernel: h_node = MLP(x) (bf16), cent = x@cent_w.T+b (fp32) ----------------
__launch_bounds__(256, 3)
__global__ void node_kernel(const bf16* __restrict__ xb,
                            const bf16* __restrict__ w1, const float* __restrict__ b1,
                            const bf16* __restrict__ w2, const float* __restrict__ b2,
                            const bf16* __restrict__ wc, const float* __restrict__ bc,
                            bf16* __restrict__ h_node, float* __restrict__ cent) {
    const int S = 136;
    __shared__ __align__(16) bf16 sX[64 * S];
    __shared__ __align__(16) bf16 sH[64 * S];
    const int tid = threadIdx.x;
    const int m0 = blockIdx.x * 64;
    {
        int e = tid >> 2, p = tid & 3;
        int gm = m0 + e;
        uint4 z = {0, 0, 0, 0};
        uint4* dst = (uint4*)(sX + e * S + p * 32);
        if (gm < NN) {
            const uint4* src = (const uint4*)(xb + (size_t)gm * 128 + p * 32);
#pragma unroll
            for (int j = 0; j < 4; ++j) dst[j] = src[j];
        } else {
#pragma unroll
            for (int j = 0; j < 4; ++j) dst[j] = z;
        }
    }
    __syncthreads();
    const int lane = tid & 63, wave = tid >> 6, t16 = lane & 15, quad = lane >> 4;
    const int n0 = wave * 32, koff = quad * 8;
    const f32x4 z4 = {0.f, 0.f, 0.f, 0.f};
    f32x4 acc[4][2];

    // H1 = relu(x @ w1^T + b1)
#pragma unroll
    for (int mt = 0; mt < 4; ++mt) { acc[mt][0] = z4; acc[mt][1] = z4; }
#pragma unroll
    for (int ks = 0; ks < 4; ++ks) {
        bf16x8 bb0 = *(const bf16x8*)(w1 + (n0 + t16) * 128 + ks * 32 + koff);
        bf16x8 bb1 = *(const bf16x8*)(w1 + (n0 + 16 + t16) * 128 + ks * 32 + koff);
#pragma unroll
        for (int mt = 0; mt < 4; ++mt) {
            bf16x8 a = *(const bf16x8*)(sX + (mt * 16 + t16) * S + ks * 32 + koff);
            acc[mt][0] = mfma16(a, bb0, acc[mt][0]);
            acc[mt][1] = mfma16(a, bb1, acc[mt][1]);
        }
    }
    {
        float bi0 = b1[n0 + t16], bi1 = b1[n0 + 16 + t16];
#pragma unroll
        for (int mt = 0; mt < 4; ++mt)
#pragma unroll
            for (int nt = 0; nt < 2; ++nt) {
                int n = n0 + nt * 16 + t16;
                float bb = nt ? bi1 : bi0;
#pragma unroll
                for (int r = 0; r < 4; ++r) {
                    float v = acc[mt][nt][r] + bb;
                    sH[(mt * 16 + quad * 4 + r) * S + n] = (bf16)(v > 0.f ? v : 0.f);
                }
            }
    }
    __syncthreads();

    // h_node = H1 @ w2^T + b2  (bf16 out)
#pragma unroll
    for (int mt = 0; mt < 4; ++mt) { acc[mt][0] = z4; acc[mt][1] = z4; }
#pragma unroll
    for (int ks = 0; ks < 4; ++ks) {
        bf16x8 bb0 = *(const bf16x8*)(w2 + (n0 + t16) * 128 + ks * 32 + koff);
        bf16x8 bb1 = *(const bf16x8*)(w2 + (n0 + 16 + t16) * 128 + ks * 32 + koff);
#pragma unroll
        for (int mt = 0; mt < 4; ++mt) {
            bf16x8 a = *(const bf16x8*)(sH + (mt * 16 + t16) * S + ks * 32 + koff);
            acc[mt][0] = mfma16(a, bb0, acc[mt][0]);
            acc[mt][1] = mfma16(a, bb1, acc[mt][1]);
        }
    }
    {
        float bi0 = b2[n0 + t16], bi1 = b2[n0 + 16 + t16];
#pragma unroll
        for (int mt = 0; mt < 4; ++mt)
#pragma unroll
            for (int nt = 0; nt < 2; ++nt) {
                int n = n0 + nt * 16 + t16;
                float bb = nt ? bi1 : bi0;
#pragma unroll
                for (int r = 0; r < 4; ++r) {
                    int gm = m0 + mt * 16 + quad * 4 + r;
                    if (gm < NN) h_node[(size_t)gm * 128 + n] = (bf16)(acc[mt][nt][r] + bb);
                }
            }
    }

    // cent = x @ wc^T + bc  (fp32 out)
#pragma unroll
    for (int mt = 0; mt < 4; ++mt) { acc[mt][0] = z4; acc[mt][1] = z4; }
#pragma unroll
    for (int ks = 0; ks < 4; ++ks) {
        bf16x8 bb0 = *(const bf16x8*)(wc + (n0 + t16) * 128 + ks * 32 + koff);
        bf16x8 bb1 = *(const bf16x8*)(wc + (n0 + 16 + t16) * 128 + ks * 32 + koff);
#pragma unroll
        for (int mt = 0; mt < 4; ++mt) {
            bf16x8 a = *(const bf16x8*)(sX + (mt * 16 + t16) * S + ks * 32 + koff);
            acc[mt][0] = mfma16(a, bb0, acc[mt][0]);
            acc[mt][1] = mfma16(a, bb1, acc[mt][1]);
        }
    }
    {
        float bi0 = bc[n0 + t16], bi1 = bc[n0 + 16 + t16];
#pragma unroll
        for (int mt = 0; mt < 4; ++mt)
#pragma unroll
            for (int nt = 0; nt < 2; ++nt) {
                int n = n0 + nt * 16 + t16;
                float bb = nt ? bi1 : bi0;
#pragma unroll
                for (int r = 0; r < 4; ++r) {
                    int gm = m0 + mt * 16 + quad * 4 + r;
                    if (gm < NN) cent[(size_t)gm * 128 + n] = acc[mt][nt][r] + bb;
                }
            }
    }
}

// ---------------- fused edge kernel ----------------
__launch_bounds__(256, 3)
__global__ void edge_kernel(const float* __restrict__ edge_attr,
                            const int* __restrict__ erow, const int* __restrict__ ecol,
                            const bf16* __restrict__ xb, const bf16* __restrict__ hnode,
                            const bf16* __restrict__ we1, const float* __restrict__ be1,
                            const bf16* __restrict__ we2, const float* __restrict__ be2,
                            const bf16* __restrict__ wm, const float* __restrict__ bm,
                            const bf16* __restrict__ wg1, const float* __restrict__ bg1,
                            const bf16* __restrict__ wg2, const float* __restrict__ bg2,
                            float* __restrict__ aggr) {
    const int SE = 72, S = 136;
    __shared__ __align__(16) bf16 sEA[64 * SE];
    __shared__ __align__(16) bf16 sX[64 * S];
    __shared__ __align__(16) bf16 sT[64 * S];
    __shared__ int rowS[64], colS[64];
    const int tid = threadIdx.x;
    const int e0 = blockIdx.x * 64;
    if (tid < 64) { rowS[tid] = erow[e0 + tid]; colS[tid] = ecol[e0 + tid]; }
    __syncthreads();
#pragma unroll
    for (int i = 0; i < 4; ++i) {
        int idx = tid * 4 + i * 1024;
        int e = idx >> 6, k = idx & 63;
        f32x4 v = *(const f32x4*)(edge_attr + (size_t)(e0 + e) * 64 + k);
        bf16x4 o;
        o[0] = (bf16)v[0]; o[1] = (bf16)v[1]; o[2] = (bf16)v[2]; o[3] = (bf16)v[3];
        *(bf16x4*)(sEA + e * SE + k) = o;
    }
    {
        int e = tid >> 2, p = tid & 3;
        const uint4* src = (const uint4*)(xb + (size_t)colS[e] * 128 + p * 32);
        uint4* dst = (uint4*)(sX + e * S + p * 32);
#pragma unroll
        for (int j = 0; j < 4; ++j) dst[j] = src[j];
    }
    __syncthreads();
    const int lane = tid & 63, wave = tid >> 6, t16 = lane & 15, quad = lane >> 4;
    const int n0 = wave * 32, koff = quad * 8;
    const f32x4 z4 = {0.f, 0.f, 0.f, 0.f};
    f32x4 acc[4][2];

    // ---- gate hidden ----
#pragma unroll
    for (int mt = 0; mt < 4; ++mt) { acc[mt][0] = z4; acc[mt][1] = z4; }
#pragma unroll
    for (int ks = 0; ks < 2; ++ks) {
        bf16x8 bb0 = *(const bf16x8*)(wg1 + (n0 + t16) * 192 + ks * 32 + koff);
        bf16x8 bb1 = *(const bf16x8*)(wg1 + (n0 + 16 + t16) * 192 + ks * 32 + koff);
#pragma unroll
        for (int mt = 0; mt < 4; ++mt) {
            bf16x8 a = *(const bf16x8*)(sEA + (mt * 16 + t16) * SE + ks * 32 + koff);
            acc[mt][0] = mfma16(a, bb0, acc[mt][0]);
            acc[mt][1] = mfma16(a, bb1, acc[mt][1]);
        }
    }
#pragma unroll
    for (int ks = 0; ks < 4; ++ks) {
        bf16x8 bb0 = *(const bf16x8*)(wg1 + (n0 + t16) * 192 + 64 + ks * 32 + koff);
        bf16x8 bb1 = *(const bf16x8*)(wg1 + (n0 + 16 + t16) * 192 + 64 + ks * 32 + koff);
#pragma unroll
        for (int mt = 0; mt < 4; ++mt) {
            bf16x8 a = *(const bf16x8*)(sX + (mt * 16 + t16) * S + ks * 32 + koff);
            acc[mt][0] = mfma16(a, bb0, acc[mt][0]);
            acc[mt][1] = mfma16(a, bb1, acc[mt][1]);
        }
    }
    {
        float bi0 = bg1[n0 + t16], bi1 = bg1[n0 + 16 + t16];
#pragma unroll
        for (int mt = 0; mt < 4; ++mt)
#pragma unroll
            for (int nt = 0; nt < 2; ++nt) {
                int n = n0 + nt * 16 + t16;
                float bb = nt ? bi1 : bi0;
#pragma unroll
                for (int r = 0; r < 4; ++r) {
                    float v = acc[mt][nt][r] + bb;
                    sT[(mt * 16 + quad * 4 + r) * S + n] = (bf16)(v > 0.f ? v : 0.f);
                }
            }
    }
    __syncthreads();

    uint4 hreg[4];
    {
        int e = tid >> 2, p = tid & 3;
        const uint4* src = (const uint4*)(hnode + (size_t)colS[e] * 128 + p * 32);
#pragma unroll
        for (int j = 0; j < 4; ++j) hreg[j] = src[j];
    }

    // ---- gate out + sigmoid (kept in fp32 registers for precision) ----
#pragma unroll
    for (int mt = 0; mt < 4; ++mt) { acc[mt][0] = z4; acc[mt][1] = z4; }
#pragma unroll
    for (int ks = 0; ks < 4; ++ks) {
        bf16x8 bb0 = *(const bf16x8*)(wg2 + (n0 + t16) * 128 + ks * 32 + koff);
        bf16x8 bb1 = *(const bf16x8*)(wg2 + (n0 + 16 + t16) * 128 + ks * 32 + koff);
#pragma unroll
        for (int mt = 0; mt < 4; ++mt) {
            bf16x8 a = *(const bf16x8*)(sT + (mt * 16 + t16) * S + ks * 32 + koff);
            acc[mt][0] = mfma16(a, bb0, acc[mt][0]);
            acc[mt][1] = mfma16(a, bb1, acc[mt][1]);
        }
    }
    f32x4 gsig[4][2];
    {
        float bi0 = bg2[n0 + t16], bi1 = bg2[n0 + 16 + t16];
#pragma unroll
        for (int mt = 0; mt < 4; ++mt)
#pragma unroll
            for (int nt = 0; nt < 2; ++nt) {
                float bb = nt ? bi1 : bi0;
#pragma unroll
                for (int r = 0; r < 4; ++r) {
                    float v = acc[mt][nt][r] + bb;
                    gsig[mt][nt][r] = 1.f / (1.f + __expf(-v));
                }
            }
    }
    {
        int e = tid >> 2, p = tid & 3;
        uint4* dst = (uint4*)(sX + e * S + p * 32);
#pragma unroll
        for (int j = 0; j < 4; ++j) dst[j] = hreg[j];
    }
    __syncthreads();

    // ---- edge hidden ----
#pragma unroll
    for (int mt = 0; mt < 4; ++mt) { acc[mt][0] = z4; acc[mt][1] = z4; }
#pragma unroll
    for (int ks = 0; ks < 2; ++ks) {
        bf16x8 bb0 = *(const bf16x8*)(we1 + (n0 + t16) * 64 + ks * 32 + koff);
        bf16x8 bb1 = *(const bf16x8*)(we1 + (n0 + 16 + t16) * 64 + ks * 32 + koff);
#pragma unroll
        for (int mt = 0; mt < 4; ++mt) {
            bf16x8 a = *(const bf16x8*)(sEA + (mt * 16 + t16) * SE + ks * 32 + koff);
            acc[mt][0] = mfma16(a, bb0, acc[mt][0]);
            acc[mt][1] = mfma16(a, bb1, acc[mt][1]);
        }
    }
    {
        float bi0 = be1[n0 + t16], bi1 = be1[n0 + 16 + t16];
#pragma unroll
        for (int mt = 0; mt < 4; ++mt)
#pragma unroll
            for (int nt = 0; nt < 2; ++nt) {
                int n = n0 + nt * 16 + t16;
                float bb = nt ? bi1 : bi0;
#pragma unroll
                for (int r = 0; r < 4; ++r) {
                    float v = acc[mt][nt][r] + bb;
                    sT[(mt * 16 + quad * 4 + r) * S + n] = (bf16)(v > 0.f ? v : 0.f);
                }
            }
    }
    __syncthreads();

    // ---- edge out + P (P kept fp32 in acc; then split hi/lo into sT/sX) ----
#pragma unroll
    for (int mt = 0; mt < 4; ++mt) { acc[mt][0] = z4; acc[mt][1] = z4; }
#pragma unroll
    for (int ks = 0; ks < 4; ++ks) {
        bf16x8 bb0 = *(const bf16x8*)(we2 + (n0 + t16) * 128 + ks * 32 + koff);
        bf16x8 bb1 = *(const bf16x8*)(we2 + (n0 + 16 + t16) * 128 + ks * 32 + koff);
#pragma unroll
        for (int mt = 0; mt < 4; ++mt) {
            bf16x8 a = *(const bf16x8*)(sT + (mt * 16 + t16) * S + ks * 32 + koff);
            acc[mt][0] = mfma16(a, bb0, acc[mt][0]);
            acc[mt][1] = mfma16(a, bb1, acc[mt][1]);
        }
    }
    {
        float bi0 = be2[n0 + t16], bi1 = be2[n0 + 16 + t16];
#pragma unroll
        for (int mt = 0; mt < 4; ++mt)
#pragma unroll
            for (int nt = 0; nt < 2; ++nt) {
                int n = n0 + nt * 16 + t16;
                float bb = nt ? bi1 : bi0;
#pragma unroll
                for (int r = 0; r < 4; ++r) {
                    float v = acc[mt][nt][r] + bb;
                    float hv = (float)sX[(mt * 16 + quad * 4 + r) * S + n];
                    acc[mt][nt][r] = v * hv;   // P in fp32, held in-place
                }
            }
    }
    __syncthreads();
    // split-precision store: P_hi -> sT, P_lo -> sX (sX is dead after hv reads)
#pragma unroll
    for (int mt = 0; mt < 4; ++mt)
#pragma unroll
        for (int nt = 0; nt < 2; ++nt) {
            int n = n0 + nt * 16 + t16;
#pragma unroll
            for (int r = 0; r < 4; ++r) {
                float p = acc[mt][nt][r];
                bf16 hi = (bf16)p;
                sT[(mt * 16 + quad * 4 + r) * S + n] = hi;
                sX[(mt * 16 + quad * 4 + r) * S + n] = (bf16)(p - (float)hi);
            }
        }
    __syncthreads();

    // ---- msg (two passes: P_hi @ W + P_lo @ W) + fp32 gate + scatter ----
#pragma unroll
    for (int mt = 0; mt < 4; ++mt) { acc[mt][0] = z4; acc[mt][1] = z4; }
#pragma unroll
    for (int ks = 0; ks < 4; ++ks) {
        bf16x8 bb0 = *(const bf16x8*)(wm + (n0 + t16) * 128 + ks * 32 + koff);
        bf16x8 bb1 = *(const bf16x8*)(wm + (n0 + 16 + t16) * 128 + ks * 32 + koff);
#pragma unroll
        for (int mt = 0; mt < 4; ++mt) {
            bf16x8 a = *(const bf16x8*)(sT + (mt * 16 + t16) * S + ks * 32 + koff);
            acc[mt][0] = mfma16(a, bb0, acc[mt][0]);
            acc[mt][1] = mfma16(a, bb1, acc[mt][1]);
        }
    }
#pragma unroll
    for (int ks = 0; ks < 4; ++ks) {
        bf16x8 bb0 = *(const bf16x8*)(wm + (n0 + t16) * 128 + ks * 32 + koff);
        bf16x8 bb1 = *(const bf16x8*)(wm + (n0 + 16 + t16) * 128 + ks * 32 + koff);
#pragma unroll
        for (int mt = 0; mt < 4; ++mt) {
            bf16x8 a = *(const bf16x8*)(sX + (mt * 16 + t16) * S + ks * 32 + koff);
            acc[mt][0] = mfma16(a, bb0, acc[mt][0]);
            acc[mt][1] = mfma16(a, bb1, acc[mt][1]);
        }
    }
    {
        float bi0 = bm[n0 + t16], bi1 = bm[n0 + 16 + t16];
#pragma unroll
        for (int mt = 0; mt < 4; ++mt)
#pragma unroll
            for (int nt = 0; nt < 2; ++nt) {
                int n = n0 + nt * 16 + t16;
                float bb = nt ? bi1 : bi0;
#pragma unroll
                for (int r = 0; r < 4; ++r) {
                    int mloc = mt * 16 + quad * 4 + r;
                    float v = (acc[mt][nt][r] + bb) * gsig[mt][nt][r];
                    atomicAdd(aggr + (size_t)rowS[mloc] * 128 + n, v);
                }
            }
    }
}

// ---------------- final kernel ----------------
__launch_bounds__(256, 3)
__global__ void final_kernel(const float* __restrict__ cent, const float* __restrict__ aggr,
                             const float* __restrict__ lng, const float* __restrict__ lnb,
                             const bf16* __restrict__ wo, const float* __restrict__ bo,
                             float* __restrict__ out) {
    const int S = 136;
    __shared__ __align__(16) bf16 sA[128 * S];
    const int tid = threadIdx.x;
    const int m0 = blockIdx.x * 128;
    {
        int r = tid >> 1, h = tid & 1;
        int gm = m0 + r;
        f32x4 vb[16];
        float sum = 0.f, sq = 0.f;
        if (gm < NN) {
            const f32x4* c4 = (const f32x4*)(cent + (size_t)gm * 128 + h * 64);
            const f32x4* a4 = (const f32x4*)(aggr + (size_t)gm * 128 + h * 64);
#pragma unroll
            for (int j = 0; j < 16; ++j) {
                f32x4 v = c4[j] + a4[j];
                vb[j] = v;
                sum += v[0] + v[1] + v[2] + v[3];
                sq += v[0] * v[0] + v[1] * v[1] + v[2] * v[2] + v[3] * v[3];
            }
        } else {
            f32x4 z = {0.f, 0.f, 0.f, 0.f};
#pragma unroll
            for (int j = 0; j < 16; ++j) vb[j] = z;
        }
        sum += __shfl_xor(sum, 1);
        sq += __shfl_xor(sq, 1);
        float mu = sum * (1.f / 128.f);
        float var = sq * (1.f / 128.f) - mu * mu;
        float rs = rsqrtf(var + 1e-5f);
#pragma unroll
        for (int j = 0; j < 16; ++j) {
            bf16x4 o;
#pragma unroll
            for (int c = 0; c < 4; ++c) {
                int k = h * 64 + j * 4 + c;
                float y = (vb[j][c] - mu) * rs * lng[k] + lnb[k];
                y = y > 0.f ? y : 0.f;
                o[c] = (bf16)(gm < NN ? y : 0.f);
            }
            *(bf16x4*)(sA + r * S + h * 64 + j * 4) = o;
        }
    }
    __syncthreads();
    const int lane = tid & 63, wave = tid >> 6, t16 = lane & 15, quad = lane >> 4;
    const int n0 = wave * 32, koff = quad * 8;
    const f32x4 z4 = {0.f, 0.f, 0.f, 0.f};
    f32x4 acc[8][2];
#pragma unroll
    for (int mt = 0; mt < 8; ++mt) { acc[mt][0] = z4; acc[mt][1] = z4; }
#pragma unroll
    for (int ks = 0; ks < 4; ++ks) {
        bf16x8 bb0 = *(const bf16x8*)(wo + (n0 + t16) * 128 + ks * 32 + koff);
        bf16x8 bb1 = *(const bf16x8*)(wo + (n0 + 16 + t16) * 128 + ks * 32 + koff);
#pragma unroll
        for (int mt = 0; mt < 8; ++mt) {
            bf16x8 a = *(const bf16x8*)(sA + (mt * 16 + t16) * S + ks * 32 + koff);
            acc[mt][0] = mfma16(a, bb0, acc[mt][0]);
            acc[mt][1] = mfma16(a, bb1, acc[mt][1]);
        }
    }
    {
        float bi0 = bo[n0 + t16], bi1 = bo[n0 + 16 + t16];
#pragma unroll
        for (int mt = 0; mt < 8; ++mt)
#pragma unroll
            for (int nt = 0; nt < 2; ++nt) {
                int n = n0 + nt * 16 + t16;
                float bb = nt ? bi1 : bi0;
#pragma unroll
                for (int r = 0; r < 4; ++r) {
                    int gm = m0 + mt * 16 + quad * 4 + r;
                    if (gm < NN) out[(size_t)gm * 128 + n] = acc[mt][nt][r] + bb;
                }
            }
    }
}

extern "C" void kernel_launch(void* const* d_in, const int* in_sizes, int n_in,
                              void* d_out, int out_size, void* d_ws, size_t ws_size,
                              hipStream_t stream) {
    bf16* wsb = (bf16*)d_ws;
    bf16* nw1 = wsb + 0;
    bf16* nw2 = wsb + 16384;
    bf16* cw = wsb + 32768;
    bf16* ew1 = wsb + 49152;
    bf16* ew2 = wsb + 57344;
    bf16* mw = wsb + 73728;
    bf16* gw1 = wsb + 90112;
    bf16* gw2 = wsb + 114688;
    bf16* ow = wsb + 131072;
    bf16* xb = wsb + 147456;
    bf16* hb = xb + (size_t)NN * 128;
    float* cent = (float*)(hb + (size_t)NN * 128);
    float* aggr = cent + (size_t)NN * 128;

    auto cv = [&](int idx, bf16* dst, int n) {
        cvt_kernel<<<(n / 4 + 255) / 256, 256, 0, stream>>>((const float*)d_in[idx], dst, n / 4);
    };
    cv(4, nw1, 16384);
    cv(6, nw2, 16384);
    cv(18, cw, 16384);
    cv(8, ew1, 8192);
    cv(10, ew2, 16384);
    cv(12, mw, 16384);
    cv(14, gw1, 24576);
    cv(16, gw2, 16384);
    cv(22, ow, 16384);
    cv(0, xb, NN * 128);
    hipMemsetAsync(aggr, 0, (size_t)NN * 128 * sizeof(float), stream);

    node_kernel<<<(NN + 63) / 64, 256, 0, stream>>>(
        xb, nw1, (const float*)d_in[5], nw2, (const float*)d_in[7],
        cw, (const float*)d_in[19], hb, cent);

    const int* ei = (const int*)d_in[2];
    edge_kernel<<<NE / 64, 256, 0, stream>>>(
        (const float*)d_in[3], ei, ei + NE, xb, hb,
        ew1, (const float*)d_in[9], ew2, (const float*)d_in[11],
        mw, (const float*)d_in[13], gw1, (const float*)d_in[15],
        gw2, (const float*)d_in[17], aggr);

    final_kernel<<<(NN + 127) / 128, 256, 0, stream>>>(
        cent, aggr, (const float*)d_in[20], (const float*)d_in[21],
        ow, (const float*)d_in[23], (float*)d_out);
}

// Round 2
// 1401.645 us; speedup vs baseline: 1.0327x; 1.0327x over previous
//
#include <hip/hip_runtime.h>

#define NN 100000
#define NE 1600000

typedef __bf16 bf16;
typedef bf16 bf16x8 __attribute__((ext_vector_type(8)));
typedef bf16 bf16x4 __attribute__((ext_vector_type(4)));
typedef float f32x4 __attribute__((ext_vector_type(4)));

__device__ __forceinline__ f32x4 mfma16(bf16x8 a, bf16x8 b, f32x4 c) {
    return __builtin_amdgcn_mfma_f32_16x16x32_bf16(a, b, c, 0, 0, 0);
}

// ---------------- fp32 -> bf16 conversion (weights, x) ----------------
__global__ void cvt_kernel(const float* __restrict__ s, bf16* __restrict__ d, int n4) {
    int i = blockIdx.x * 256 + threadIdx.x;
    if (i < n4) {
        f32x4 v = ((const f32x4*)s)[i];
        bf16x4 o;
        o[0] = (bf16)v[0]; o[1] = (bf16)v[1]; o[2] = (bf16)v[2]; o[3] = (bf16)v[3];
        ((bf16x4*)d)[i] = o;
    }
}

// ---------------- node kernel: h_node = MLP(x) (bf16), cent = x@cent_w.T+b (fp32),
// ----------------              gx = x @ gate_w1[:,64:192].T (fp32, no bias) ----------------
__launch_bounds__(256, 3)
__global__ void node_kernel(const bf16* __restrict__ xb,
                            const bf16* __restrict__ w1, const float* __restrict__ b1,
                            const bf16* __restrict__ w2, const float* __restrict__ b2,
                            const bf16* __restrict__ wc, const float* __restrict__ bc,
                            const bf16* __restrict__ wg1,
                            bf16* __restrict__ h_node, float* __restrict__ cent,
                            float* __restrict__ gx) {
    const int S = 136;
    __shared__ __align__(16) bf16 sX[64 * S];
    __shared__ __align__(16) bf16 sH[64 * S];
    const int tid = threadIdx.x;
    const int m0 = blockIdx.x * 64;
    {
        int e = tid >> 2, p = tid & 3;
        int gm = m0 + e;
        uint4 z = {0, 0, 0, 0};
        uint4* dst = (uint4*)(sX + e * S + p * 32);
        if (gm < NN) {
            const uint4* src = (const uint4*)(xb + (size_t)gm * 128 + p * 32);
#pragma unroll
            for (int j = 0; j < 4; ++j) dst[j] = src[j];
        } else {
#pragma unroll
            for (int j = 0; j < 4; ++j) dst[j] = z;
        }
    }
    __syncthreads();
    const int lane = tid & 63, wave = tid >> 6, t16 = lane & 15, quad = lane >> 4;
    const int n0 = wave * 32, koff = quad * 8;
    const f32x4 z4 = {0.f, 0.f, 0.f, 0.f};
    f32x4 acc[4][2];

    // H1 = relu(x @ w1^T + b1)
#pragma unroll
    for (int mt = 0; mt < 4; ++mt) { acc[mt][0] = z4; acc[mt][1] = z4; }
#pragma unroll
    for (int ks = 0; ks < 4; ++ks) {
        bf16x8 bb0 = *(const bf16x8*)(w1 + (n0 + t16) * 128 + ks * 32 + koff);
        bf16x8 bb1 = *(const bf16x8*)(w1 + (n0 + 16 + t16) * 128 + ks * 32 + koff);
#pragma unroll
        for (int mt = 0; mt < 4; ++mt) {
            bf16x8 a = *(const bf16x8*)(sX + (mt * 16 + t16) * S + ks * 32 + koff);
            acc[mt][0] = mfma16(a, bb0, acc[mt][0]);
            acc[mt][1] = mfma16(a, bb1, acc[mt][1]);
        }
    }
    {
        float bi0 = b1[n0 + t16], bi1 = b1[n0 + 16 + t16];
#pragma unroll
        for (int mt = 0; mt < 4; ++mt)
#pragma unroll
            for (int nt = 0; nt < 2; ++nt) {
                int n = n0 + nt * 16 + t16;
                float bb = nt ? bi1 : bi0;
#pragma unroll
                for (int r = 0; r < 4; ++r) {
                    float v = acc[mt][nt][r] + bb;
                    sH[(mt * 16 + quad * 4 + r) * S + n] = (bf16)(v > 0.f ? v : 0.f);
                }
            }
    }
    __syncthreads();

    // h_node = H1 @ w2^T + b2  (bf16 out)
#pragma unroll
    for (int mt = 0; mt < 4; ++mt) { acc[mt][0] = z4; acc[mt][1] = z4; }
#pragma unroll
    for (int ks = 0; ks < 4; ++ks) {
        bf16x8 bb0 = *(const bf16x8*)(w2 + (n0 + t16) * 128 + ks * 32 + koff);
        bf16x8 bb1 = *(const bf16x8*)(w2 + (n0 + 16 + t16) * 128 + ks * 32 + koff);
#pragma unroll
        for (int mt = 0; mt < 4; ++mt) {
            bf16x8 a = *(const bf16x8*)(sH + (mt * 16 + t16) * S + ks * 32 + koff);
            acc[mt][0] = mfma16(a, bb0, acc[mt][0]);
            acc[mt][1] = mfma16(a, bb1, acc[mt][1]);
        }
    }
    {
        float bi0 = b2[n0 + t16], bi1 = b2[n0 + 16 + t16];
#pragma unroll
        for (int mt = 0; mt < 4; ++mt)
#pragma unroll
            for (int nt = 0; nt < 2; ++nt) {
                int n = n0 + nt * 16 + t16;
                float bb = nt ? bi1 : bi0;
#pragma unroll
                for (int r = 0; r < 4; ++r) {
                    int gm = m0 + mt * 16 + quad * 4 + r;
                    if (gm < NN) h_node[(size_t)gm * 128 + n] = (bf16)(acc[mt][nt][r] + bb);
                }
            }
    }

    // cent = x @ wc^T + bc  (fp32 out)
#pragma unroll
    for (int mt = 0; mt < 4; ++mt) { acc[mt][0] = z4; acc[mt][1] = z4; }
#pragma unroll
    for (int ks = 0; ks < 4; ++ks) {
        bf16x8 bb0 = *(const bf16x8*)(wc + (n0 + t16) * 128 + ks * 32 + koff);
        bf16x8 bb1 = *(const bf16x8*)(wc + (n0 + 16 + t16) * 128 + ks * 32 + koff);
#pragma unroll
        for (int mt = 0; mt < 4; ++mt) {
            bf16x8 a = *(const bf16x8*)(sX + (mt * 16 + t16) * S + ks * 32 + koff);
            acc[mt][0] = mfma16(a, bb0, acc[mt][0]);
            acc[mt][1] = mfma16(a, bb1, acc[mt][1]);
        }
    }
    {
        float bi0 = bc[n0 + t16], bi1 = bc[n0 + 16 + t16];
#pragma unroll
        for (int mt = 0; mt < 4; ++mt)
#pragma unroll
            for (int nt = 0; nt < 2; ++nt) {
                int n = n0 + nt * 16 + t16;
                float bb = nt ? bi1 : bi0;
#pragma unroll
                for (int r = 0; r < 4; ++r) {
                    int gm = m0 + mt * 16 + quad * 4 + r;
                    if (gm < NN) cent[(size_t)gm * 128 + n] = acc[mt][nt][r] + bb;
                }
            }
    }

    // gx = x @ wg1[:,64:192]^T  (fp32 out, NO bias — bias added in edge kernel)
#pragma unroll
    for (int mt = 0; mt < 4; ++mt) { acc[mt][0] = z4; acc[mt][1] = z4; }
#pragma unroll
    for (int ks = 0; ks < 4; ++ks) {
        bf16x8 bb0 = *(const bf16x8*)(wg1 + (n0 + t16) * 192 + 64 + ks * 32 + koff);
        bf16x8 bb1 = *(const bf16x8*)(wg1 + (n0 + 16 + t16) * 192 + 64 + ks * 32 + koff);
#pragma unroll
        for (int mt = 0; mt < 4; ++mt) {
            bf16x8 a = *(const bf16x8*)(sX + (mt * 16 + t16) * S + ks * 32 + koff);
            acc[mt][0] = mfma16(a, bb0, acc[mt][0]);
            acc[mt][1] = mfma16(a, bb1, acc[mt][1]);
        }
    }
#pragma unroll
    for (int mt = 0; mt < 4; ++mt)
#pragma unroll
        for (int nt = 0; nt < 2; ++nt) {
            int n = n0 + nt * 16 + t16;
#pragma unroll
            for (int r = 0; r < 4; ++r) {
                int gm = m0 + mt * 16 + quad * 4 + r;
                if (gm < NN) gx[(size_t)gm * 128 + n] = acc[mt][nt][r];
            }
        }
}

// ---------------- fused edge kernel ----------------
__launch_bounds__(256, 3)
__global__ void edge_kernel(const float* __restrict__ edge_attr,
                            const int* __restrict__ erow, const int* __restrict__ ecol,
                            const bf16* __restrict__ hnode, const float* __restrict__ gx,
                            const bf16* __restrict__ we1, const float* __restrict__ be1,
                            const bf16* __restrict__ we2, const float* __restrict__ be2,
                            const bf16* __restrict__ wm, const float* __restrict__ bm,
                            const bf16* __restrict__ wg1, const float* __restrict__ bg1,
                            const bf16* __restrict__ wg2, const float* __restrict__ bg2,
                            float* __restrict__ aggr) {
    const int SE = 72, S = 136;
    __shared__ __align__(16) bf16 sEA[64 * SE];
    __shared__ __align__(16) bf16 sX[64 * S];   // hnode[col], later P_lo
    __shared__ __align__(16) bf16 sT[64 * S];
    __shared__ int rowS[64], colS[64];
    const int tid = threadIdx.x;
    const int e0 = blockIdx.x * 64;
    if (tid < 64) { rowS[tid] = erow[e0 + tid]; colS[tid] = ecol[e0 + tid]; }
    __syncthreads();
    // stage edge_attr (cvt fp32->bf16) and hnode gather, overlapped
#pragma unroll
    for (int i = 0; i < 4; ++i) {
        int idx = tid * 4 + i * 1024;
        int e = idx >> 6, k = idx & 63;
        f32x4 v = *(const f32x4*)(edge_attr + (size_t)(e0 + e) * 64 + k);
        bf16x4 o;
        o[0] = (bf16)v[0]; o[1] = (bf16)v[1]; o[2] = (bf16)v[2]; o[3] = (bf16)v[3];
        *(bf16x4*)(sEA + e * SE + k) = o;
    }
    {
        int e = tid >> 2, p = tid & 3;
        const uint4* src = (const uint4*)(hnode + (size_t)colS[e] * 128 + p * 32);
        uint4* dst = (uint4*)(sX + e * S + p * 32);
#pragma unroll
        for (int j = 0; j < 4; ++j) dst[j] = src[j];
    }
    __syncthreads();
    const int lane = tid & 63, wave = tid >> 6, t16 = lane & 15, quad = lane >> 4;
    const int n0 = wave * 32, koff = quad * 8;
    const f32x4 z4 = {0.f, 0.f, 0.f, 0.f};
    f32x4 acc[4][2];

    // ---- phase A: gate hidden = relu(ea @ wg1[:, :64]^T + gx[col] + bg1) ----
    // issue gx gathers first so they hide under the MFMA K-loop
    float gval[4][2][4];
#pragma unroll
    for (int mt = 0; mt < 4; ++mt)
#pragma unroll
        for (int r = 0; r < 4; ++r) {
            const float* grow = gx + (size_t)colS[mt * 16 + quad * 4 + r] * 128;
            gval[mt][0][r] = grow[n0 + t16];
            gval[mt][1][r] = grow[n0 + 16 + t16];
        }
#pragma unroll
    for (int mt = 0; mt < 4; ++mt) { acc[mt][0] = z4; acc[mt][1] = z4; }
#pragma unroll
    for (int ks = 0; ks < 2; ++ks) {
        bf16x8 bb0 = *(const bf16x8*)(wg1 + (n0 + t16) * 192 + ks * 32 + koff);
        bf16x8 bb1 = *(const bf16x8*)(wg1 + (n0 + 16 + t16) * 192 + ks * 32 + koff);
#pragma unroll
        for (int mt = 0; mt < 4; ++mt) {
            bf16x8 a = *(const bf16x8*)(sEA + (mt * 16 + t16) * SE + ks * 32 + koff);
            acc[mt][0] = mfma16(a, bb0, acc[mt][0]);
            acc[mt][1] = mfma16(a, bb1, acc[mt][1]);
        }
    }
    {
        float bi0 = bg1[n0 + t16], bi1 = bg1[n0 + 16 + t16];
#pragma unroll
        for (int mt = 0; mt < 4; ++mt)
#pragma unroll
            for (int nt = 0; nt < 2; ++nt) {
                int n = n0 + nt * 16 + t16;
                float bb = nt ? bi1 : bi0;
#pragma unroll
                for (int r = 0; r < 4; ++r) {
                    float v = acc[mt][nt][r] + bb + gval[mt][nt][r];
                    sT[(mt * 16 + quad * 4 + r) * S + n] = (bf16)(v > 0.f ? v : 0.f);
                }
            }
    }
    __syncthreads();

    // ---- phase B: gate out (reads sT) + edge hidden (reads sEA), merged issue ----
    f32x4 gsig[4][2];
#pragma unroll
    for (int mt = 0; mt < 4; ++mt) { gsig[mt][0] = z4; gsig[mt][1] = z4; acc[mt][0] = z4; acc[mt][1] = z4; }
#pragma unroll
    for (int ks = 0; ks < 4; ++ks) {
        bf16x8 bb0 = *(const bf16x8*)(wg2 + (n0 + t16) * 128 + ks * 32 + koff);
        bf16x8 bb1 = *(const bf16x8*)(wg2 + (n0 + 16 + t16) * 128 + ks * 32 + koff);
#pragma unroll
        for (int mt = 0; mt < 4; ++mt) {
            bf16x8 a = *(const bf16x8*)(sT + (mt * 16 + t16) * S + ks * 32 + koff);
            gsig[mt][0] = mfma16(a, bb0, gsig[mt][0]);
            gsig[mt][1] = mfma16(a, bb1, gsig[mt][1]);
        }
    }
#pragma unroll
    for (int ks = 0; ks < 2; ++ks) {
        bf16x8 bb0 = *(const bf16x8*)(we1 + (n0 + t16) * 64 + ks * 32 + koff);
        bf16x8 bb1 = *(const bf16x8*)(we1 + (n0 + 16 + t16) * 64 + ks * 32 + koff);
#pragma unroll
        for (int mt = 0; mt < 4; ++mt) {
            bf16x8 a = *(const bf16x8*)(sEA + (mt * 16 + t16) * SE + ks * 32 + koff);
            acc[mt][0] = mfma16(a, bb0, acc[mt][0]);
            acc[mt][1] = mfma16(a, bb1, acc[mt][1]);
        }
    }
    __syncthreads();   // all waves done reading sT
    {
        float bi0 = bg2[n0 + t16], bi1 = bg2[n0 + 16 + t16];
#pragma unroll
        for (int mt = 0; mt < 4; ++mt)
#pragma unroll
            for (int nt = 0; nt < 2; ++nt) {
                float bb = nt ? bi1 : bi0;
#pragma unroll
                for (int r = 0; r < 4; ++r) {
                    float v = gsig[mt][nt][r] + bb;
                    gsig[mt][nt][r] = 1.f / (1.f + __expf(-v));
                }
            }
    }
    {
        float bi0 = be1[n0 + t16], bi1 = be1[n0 + 16 + t16];
#pragma unroll
        for (int mt = 0; mt < 4; ++mt)
#pragma unroll
            for (int nt = 0; nt < 2; ++nt) {
                int n = n0 + nt * 16 + t16;
                float bb = nt ? bi1 : bi0;
#pragma unroll
                for (int r = 0; r < 4; ++r) {
                    float v = acc[mt][nt][r] + bb;
                    sT[(mt * 16 + quad * 4 + r) * S + n] = (bf16)(v > 0.f ? v : 0.f);
                }
            }
    }
    __syncthreads();

    // ---- phase C: edge out + P = h_edge * h_node (fp32 in acc) ----
#pragma unroll
    for (int mt = 0; mt < 4; ++mt) { acc[mt][0] = z4; acc[mt][1] = z4; }
#pragma unroll
    for (int ks = 0; ks < 4; ++ks) {
        bf16x8 bb0 = *(const bf16x8*)(we2 + (n0 + t16) * 128 + ks * 32 + koff);
        bf16x8 bb1 = *(const bf16x8*)(we2 + (n0 + 16 + t16) * 128 + ks * 32 + koff);
#pragma unroll
        for (int mt = 0; mt < 4; ++mt) {
            bf16x8 a = *(const bf16x8*)(sT + (mt * 16 + t16) * S + ks * 32 + koff);
            acc[mt][0] = mfma16(a, bb0, acc[mt][0]);
            acc[mt][1] = mfma16(a, bb1, acc[mt][1]);
        }
    }
    {
        float bi0 = be2[n0 + t16], bi1 = be2[n0 + 16 + t16];
#pragma unroll
        for (int mt = 0; mt < 4; ++mt)
#pragma unroll
            for (int nt = 0; nt < 2; ++nt) {
                int n = n0 + nt * 16 + t16;
                float bb = nt ? bi1 : bi0;
#pragma unroll
                for (int r = 0; r < 4; ++r) {
                    float v = acc[mt][nt][r] + bb;
                    float hv = (float)sX[(mt * 16 + quad * 4 + r) * S + n];
                    acc[mt][nt][r] = v * hv;
                }
            }
    }
    __syncthreads();
    // split-precision store: P_hi -> sT, P_lo -> sX (hnode dead now)
#pragma unroll
    for (int mt = 0; mt < 4; ++mt)
#pragma unroll
        for (int nt = 0; nt < 2; ++nt) {
            int n = n0 + nt * 16 + t16;
#pragma unroll
            for (int r = 0; r < 4; ++r) {
                float p = acc[mt][nt][r];
                bf16 hi = (bf16)p;
                sT[(mt * 16 + quad * 4 + r) * S + n] = hi;
                sX[(mt * 16 + quad * 4 + r) * S + n] = (bf16)(p - (float)hi);
            }
        }
    __syncthreads();

    // ---- phase D: msg = (P_hi + P_lo) @ wm^T + bm, gated, scatter ----
#pragma unroll
    for (int mt = 0; mt < 4; ++mt) { acc[mt][0] = z4; acc[mt][1] = z4; }
#pragma unroll
    for (int ks = 0; ks < 4; ++ks) {
        bf16x8 bb0 = *(const bf16x8*)(wm + (n0 + t16) * 128 + ks * 32 + koff);
        bf16x8 bb1 = *(const bf16x8*)(wm + (n0 + 16 + t16) * 128 + ks * 32 + koff);
#pragma unroll
        for (int mt = 0; mt < 4; ++mt) {
            bf16x8 a = *(const bf16x8*)(sT + (mt * 16 + t16) * S + ks * 32 + koff);
            acc[mt][0] = mfma16(a, bb0, acc[mt][0]);
            acc[mt][1] = mfma16(a, bb1, acc[mt][1]);
        }
    }
#pragma unroll
    for (int ks = 0; ks < 4; ++ks) {
        bf16x8 bb0 = *(const bf16x8*)(wm + (n0 + t16) * 128 + ks * 32 + koff);
        bf16x8 bb1 = *(const bf16x8*)(wm + (n0 + 16 + t16) * 128 + ks * 32 + koff);
#pragma unroll
        for (int mt = 0; mt < 4; ++mt) {
            bf16x8 a = *(const bf16x8*)(sX + (mt * 16 + t16) * S + ks * 32 + koff);
            acc[mt][0] = mfma16(a, bb0, acc[mt][0]);
            acc[mt][1] = mfma16(a, bb1, acc[mt][1]);
        }
    }
    {
        float bi0 = bm[n0 + t16], bi1 = bm[n0 + 16 + t16];
#pragma unroll
        for (int mt = 0; mt < 4; ++mt)
#pragma unroll
            for (int nt = 0; nt < 2; ++nt) {
                int n = n0 + nt * 16 + t16;
                float bb = nt ? bi1 : bi0;
#pragma unroll
                for (int r = 0; r < 4; ++r) {
                    int mloc = mt * 16 + quad * 4 + r;
                    float v = (acc[mt][nt][r] + bb) * gsig[mt][nt][r];
                    atomicAdd(aggr + (size_t)rowS[mloc] * 128 + n, v);
                }
            }
    }
}

// ---------------- final kernel ----------------
__launch_bounds__(256, 3)
__global__ void final_kernel(const float* __restrict__ cent, const float* __restrict__ aggr,
                             const float* __restrict__ lng, const float* __restrict__ lnb,
                             const bf16* __restrict__ wo, const float* __restrict__ bo,
                             float* __restrict__ out) {
    const int S = 136;
    __shared__ __align__(16) bf16 sA[128 * S];
    const int tid = threadIdx.x;
    const int m0 = blockIdx.x * 128;
    {
        int r = tid >> 1, h = tid & 1;
        int gm = m0 + r;
        f32x4 vb[16];
        float sum = 0.f, sq = 0.f;
        if (gm < NN) {
            const f32x4* c4 = (const f32x4*)(cent + (size_t)gm * 128 + h * 64);
            const f32x4* a4 = (const f32x4*)(aggr + (size_t)gm * 128 + h * 64);
#pragma unroll
            for (int j = 0; j < 16; ++j) {
                f32x4 v = c4[j] + a4[j];
                vb[j] = v;
                sum += v[0] + v[1] + v[2] + v[3];
                sq += v[0] * v[0] + v[1] * v[1] + v[2] * v[2] + v[3] * v[3];
            }
        } else {
            f32x4 z = {0.f, 0.f, 0.f, 0.f};
#pragma unroll
            for (int j = 0; j < 16; ++j) vb[j] = z;
        }
        sum += __shfl_xor(sum, 1);
        sq += __shfl_xor(sq, 1);
        float mu = sum * (1.f / 128.f);
        float var = sq * (1.f / 128.f) - mu * mu;
        float rs = rsqrtf(var + 1e-5f);
#pragma unroll
        for (int j = 0; j < 16; ++j) {
            bf16x4 o;
#pragma unroll
            for (int c = 0; c < 4; ++c) {
                int k = h * 64 + j * 4 + c;
                float y = (vb[j][c] - mu) * rs * lng[k] + lnb[k];
                y = y > 0.f ? y : 0.f;
                o[c] = (bf16)(gm < NN ? y : 0.f);
            }
            *(bf16x4*)(sA + r * S + h * 64 + j * 4) = o;
        }
    }
    __syncthreads();
    const int lane = tid & 63, wave = tid >> 6, t16 = lane & 15, quad = lane >> 4;
    const int n0 = wave * 32, koff = quad * 8;
    const f32x4 z4 = {0.f, 0.f, 0.f, 0.f};
    f32x4 acc[8][2];
#pragma unroll
    for (int mt = 0; mt < 8; ++mt) { acc[mt][0] = z4; acc[mt][1] = z4; }
#pragma unroll
    for (int ks = 0; ks < 4; ++ks) {
        bf16x8 bb0 = *(const bf16x8*)(wo + (n0 + t16) * 128 + ks * 32 + koff);
        bf16x8 bb1 = *(const bf16x8*)(wo + (n0 + 16 + t16) * 128 + ks * 32 + koff);
#pragma unroll
        for (int mt = 0; mt < 8; ++mt) {
            bf16x8 a = *(const bf16x8*)(sA + (mt * 16 + t16) * S + ks * 32 + koff);
            acc[mt][0] = mfma16(a, bb0, acc[mt][0]);
            acc[mt][1] = mfma16(a, bb1, acc[mt][1]);
        }
    }
    {
        float bi0 = bo[n0 + t16], bi1 = bo[n0 + 16 + t16];
#pragma unroll
        for (int mt = 0; mt < 8; ++mt)
#pragma unroll
            for (int nt = 0; nt < 2; ++nt) {
                int n = n0 + nt * 16 + t16;
                float bb = nt ? bi1 : bi0;
#pragma unroll
                for (int r = 0; r < 4; ++r) {
                    int gm = m0 + mt * 16 + quad * 4 + r;
                    if (gm < NN) out[(size_t)gm * 128 + n] = acc[mt][nt][r] + bb;
                }
            }
    }
}

extern "C" void kernel_launch(void* const* d_in, const int* in_sizes, int n_in,
                              void* d_out, int out_size, void* d_ws, size_t ws_size,
                              hipStream_t stream) {
    bf16* wsb = (bf16*)d_ws;
    bf16* nw1 = wsb + 0;
    bf16* nw2 = wsb + 16384;
    bf16* cw = wsb + 32768;
    bf16* ew1 = wsb + 49152;
    bf16* ew2 = wsb + 57344;
    bf16* mw = wsb + 73728;
    bf16* gw1 = wsb + 90112;
    bf16* gw2 = wsb + 114688;
    bf16* ow = wsb + 131072;
    bf16* xb = wsb + 147456;
    bf16* hb = xb + (size_t)NN * 128;
    float* cent = (float*)(hb + (size_t)NN * 128);
    float* aggr = cent + (size_t)NN * 128;
    float* gx = aggr + (size_t)NN * 128;

    auto cv = [&](int idx, bf16* dst, int n) {
        cvt_kernel<<<(n / 4 + 255) / 256, 256, 0, stream>>>((const float*)d_in[idx], dst, n / 4);
    };
    cv(4, nw1, 16384);
    cv(6, nw2, 16384);
    cv(18, cw, 16384);
    cv(8, ew1, 8192);
    cv(10, ew2, 16384);
    cv(12, mw, 16384);
    cv(14, gw1, 24576);
    cv(16, gw2, 16384);
    cv(22, ow, 16384);
    cv(0, xb, NN * 128);
    hipMemsetAsync(aggr, 0, (size_t)NN * 128 * sizeof(float), stream);

    node_kernel<<<(NN + 63) / 64, 256, 0, stream>>>(
        xb, nw1, (const float*)d_in[5], nw2, (const float*)d_in[7],
        cw, (const float*)d_in[19], gw1, hb, cent, gx);

    const int* ei = (const int*)d_in[2];
    edge_kernel<<<NE / 64, 256, 0, stream>>>(
        (const float*)d_in[3], ei, ei + NE, hb, gx,
        ew1, (const float*)d_in[9], ew2, (const float*)d_in[11],
        mw, (const float*)d_in[13], gw1, (const float*)d_in[15],
        gw2, (const float*)d_in[17], aggr);

    final_kernel<<<(NN + 127) / 128, 256, 0, stream>>>(
        cent, aggr, (const float*)d_in[20], (const float*)d_in[21],
        ow, (const float*)d_in[23], (float*)d_out);
}